// Round 7
// baseline (220.565 us; speedup 1.0000x reference)
//
#include <hip/hip_runtime.h>

#define BB 32
#define TT 1024
#define CCH 384
#define HH 64

typedef short short8 __attribute__((ext_vector_type(8)));
typedef float f32x4 __attribute__((ext_vector_type(4)));
typedef unsigned short ushort;

static __device__ __forceinline__ ushort f2bf(float f) {
    union { float f; unsigned u; } v; v.f = f;
    unsigned r = v.u + 0x7fff + ((v.u >> 16) & 1);
    return (ushort)(r >> 16);
}

// ---------------------------------------------------------------------------
// Kernel 1: weight swizzle (verified) + semaphore zeroing (block (0,0)).
// Runs before the persistent kernel on the same stream; the kernel boundary
// makes the zeroed semaphores visible device-wide.
// ---------------------------------------------------------------------------
__global__ void wswz(const float* __restrict__ Wk, const float* __restrict__ Wq,
                     const float* __restrict__ Wv, ushort* __restrict__ wf,
                     unsigned* __restrict__ sem) {
    const int mat = blockIdx.x, ks = blockIdx.y;
    if (mat == 0 && ks == 0 && threadIdx.x < 32) sem[threadIdx.x] = 0u;
    const float* W = (mat == 0) ? Wk : ((mat == 1) ? Wq : Wv);
    const int t = threadIdx.x;
    const int ct = t >> 6, lane = t & 63, quad = lane >> 4, l15 = lane & 15;
    const int col = ct * 16 + l15;
    short8 d;
#pragma unroll
    for (int j = 0; j < 8; ++j)
        d[j] = (short)f2bf(W[(ks * 32 + quad * 8 + j) * 64 + col]);
    *(short8*)(wf + (((mat * 12 + ks) * 4 + ct) << 9) + lane * 8) = d;
}

#define XSTR 388
#define VS_STRIDE 68
#define PSTR2 40
#define KSTR 72
#define VSTR 136

// attn epilogue (r6-verified pattern): publish (w,m) partials, combine by
// pure addition (fixed-shift softmax), normalize, store 32 q-rows.
static __device__ __forceinline__ void attn_epilogue(
    char* arena, f32x4 (&o)[2][4], float (&li)[2][4],
    int w, int quad, int l15, int t0, int b, float* __restrict__ out) {
    float* slotO = (float*)arena;              // [8][4][16][17] f32
    float* slotL = (float*)(arena + 34816);    // [8][16] f32

    __syncthreads();   // all waves done with prior arena contents

#pragma unroll
    for (int m = 0; m < 2; ++m)
#pragma unroll
        for (int r = 0; r < 4; ++r) {
            float rs = li[m][r];
#pragma unroll
            for (int off = 1; off < 16; off <<= 1)
                rs += __shfl_xor(rs, off);
            li[m][r] = rs;
        }

#pragma unroll
    for (int m = 0; m < 2; ++m) {
        const int sl = w * 2 + m;
#pragma unroll
        for (int ct = 0; ct < 4; ++ct)
#pragma unroll
            for (int r = 0; r < 4; ++r)
                slotO[(sl * 4 + ct) * 272 + (quad * 4 + r) * 17 + l15] = o[m][ct][r];
        if (l15 == 0)
#pragma unroll
            for (int r = 0; r < 4; ++r)
                slotL[sl * 16 + quad * 4 + r] = li[m][r];
    }
    __syncthreads();

    const int mh = w >> 1, cb = (w & 1) * 2;
#pragma unroll
    for (int r = 0; r < 4; ++r) {
        float lsum = 0.f;
#pragma unroll
        for (int wp = 0; wp < 4; ++wp)
            lsum += slotL[(wp * 2 + mh) * 16 + quad * 4 + r];
        const float inv = 1.0f / lsum;
        const int t = t0 + mh * 16 + quad * 4 + r;
#pragma unroll
        for (int cc = 0; cc < 2; ++cc) {
            const int ct = cb + cc;
            float v = 0.f;
#pragma unroll
            for (int wp = 0; wp < 4; ++wp)
                v += slotO[((wp * 2 + mh) * 4 + ct) * 272 + (quad * 4 + r) * 17 + l15];
            out[b * 65536 + t * 64 + ct * 16 + l15] = v * inv;
        }
    }
}

// ---------------------------------------------------------------------------
// Kernel 2: PERSISTENT fused qkv + attention. Grid = exactly 512 blocks
// (2/CU co-resident: LDS 49,664 B x 2 = 99.3 KB < 160 KB; VGPR capped 256).
// Deadlock-safe by construction: every block finishes its PRODUCER (qkv)
// work and signals BEFORE its first spin, and all blocks are resident.
//   Block gb: beta = gb>>4, s = gb&15.
//   - qkv for rows gb*64 (batch beta); threadfence + release atomicAdd
//     sem[beta] (16 producers per batch).
//   - acquire-spin until sem[beta]==16 (own batch only -> wait on the 15
//     sibling blocks; they are dispatched contiguously, wait is short).
//   - MERGED dual-job attn pass: heavy tile qtH=16+s, light qtL=15-s; light
//     tiles are a subset of heavy tiles, so each key tile is staged ONCE
//     and consumed by both jobs. Iterations/block: 5..8 (was 9); worst-CU
//     16 (was 18). Bodies are the r6-verified key-split structures.
// ---------------------------------------------------------------------------
__global__ __launch_bounds__(256, 2) void qkattn(const float* __restrict__ x,
                                                 const ushort* __restrict__ wf,
                                                 ushort* __restrict__ kb,
                                                 ushort* __restrict__ qb,
                                                 ushort* __restrict__ vtb,
                                                 float* __restrict__ out,
                                                 unsigned* __restrict__ sem) {
    __shared__ __align__(16) char arena[49664];

    const int gb = blockIdx.x;
    const int tid = threadIdx.x;
    const int w = tid >> 6, lane = tid & 63, l15 = lane & 15, quad = lane >> 4;
    const int beta = gb >> 4, sB = gb & 15;

    // ================= phase 1: QKV projection (r6-verified body) ==========
    {
        const int r0 = gb * 64;
        ushort* xs = (ushort*)arena;

#pragma unroll
        for (int kb3 = 0; kb3 < 3; ++kb3) {
            const int kbase = kb3 * 128;
            const int seg = (tid & 7) * 16;
#pragma unroll
            for (int i = 0; i < 2; ++i) {
                const int r = (tid >> 3) + 32 * i;
                const float* src = x + (size_t)(r0 + r) * CCH + kbase + seg;
                f32x4 v0 = *(const f32x4*)(src);
                f32x4 v1 = *(const f32x4*)(src + 4);
                f32x4 v2 = *(const f32x4*)(src + 8);
                f32x4 v3 = *(const f32x4*)(src + 12);
                short8 p0, p1;
#pragma unroll
                for (int j = 0; j < 4; ++j) {
                    p0[j]     = (short)f2bf(v0[j]);
                    p0[j + 4] = (short)f2bf(v1[j]);
                    p1[j]     = (short)f2bf(v2[j]);
                    p1[j + 4] = (short)f2bf(v3[j]);
                }
                *(short8*)(xs + r * XSTR + kbase + seg) = p0;
                *(short8*)(xs + r * XSTR + kbase + seg + 8) = p1;
            }
        }
        __syncthreads();

        f32x4 acc[12] = {};
        short8 bfrag[2][12];
#pragma unroll
        for (int m = 0; m < 3; ++m)
#pragma unroll
            for (int ct = 0; ct < 4; ++ct)
                bfrag[0][m * 4 + ct] = *(const short8*)(wf + (((m * 12 + 0) * 4 + ct) << 9) + lane * 8);

#pragma unroll
        for (int ks = 0; ks < 12; ++ks) {
            short8 a = *(const short8*)(xs + (w * 16 + l15) * XSTR + ks * 32 + quad * 8);
            if (ks < 11) {
#pragma unroll
                for (int m = 0; m < 3; ++m)
#pragma unroll
                    for (int ct = 0; ct < 4; ++ct)
                        bfrag[(ks + 1) & 1][m * 4 + ct] =
                            *(const short8*)(wf + (((m * 12 + ks + 1) * 4 + ct) << 9) + lane * 8);
            }
#pragma unroll
            for (int f = 0; f < 12; ++f)
                acc[f] = __builtin_amdgcn_mfma_f32_16x16x32_bf16(a, bfrag[ks & 1][f], acc[f], 0, 0, 0);
        }

#pragma unroll
        for (int ct = 0; ct < 4; ++ct) {
#pragma unroll
            for (int r = 0; r < 4; ++r) {
                int row = r0 + w * 16 + quad * 4 + r;
                int col = ct * 16 + l15;
                kb[row * 64 + col] = f2bf(acc[0 + ct][r]);
                qb[row * 64 + col] = f2bf(acc[4 + ct][r]);
            }
        }
        __syncthreads();
        ushort* vs = xs;
#pragma unroll
        for (int ct = 0; ct < 4; ++ct)
#pragma unroll
            for (int r = 0; r < 4; ++r)
                vs[(w * 16 + quad * 4 + r) * VS_STRIDE + ct * 16 + l15] = f2bf(acc[8 + ct][r]);
        __syncthreads();
        {
            const int col = tid >> 2;
            const int rbase = (tid & 3) * 16;
            short8 d0, d1;
#pragma unroll
            for (int j = 0; j < 8; ++j) {
                d0[j] = (short)vs[(rbase + j) * VS_STRIDE + col];
                d1[j] = (short)vs[(rbase + 8 + j) * VS_STRIDE + col];
            }
            const int bq = r0 >> 10;
            const int t = (r0 & 1023) + rbase;
            *(short8*)(vtb + bq * 65536 + col * 1024 + t) = d0;
            *(short8*)(vtb + bq * 65536 + col * 1024 + t + 8) = d1;
        }
    }

    // ====== producer signal + consumer wait (own batch only) ===============
    __threadfence();                      // agent-scope release of kb/qb/vtb
    __syncthreads();                      // all waves' stores fenced
    if (tid == 0) {
        __hip_atomic_fetch_add(&sem[beta], 1u, __ATOMIC_RELEASE, __HIP_MEMORY_SCOPE_AGENT);
        while (__hip_atomic_load(&sem[beta], __ATOMIC_ACQUIRE, __HIP_MEMORY_SCOPE_AGENT) < 16u)
            __builtin_amdgcn_s_sleep(8);
    }
    __syncthreads();                      // whole block released; caches inv'd

    // ================= phase 2: merged dual-job attention ==================
    {
        const int b = beta;
        const int qtH = 16 + sB, qtL = 15 - sB;
        const int t0H = qtH * 32, t0L = qtL * 32;
        const int nstH = (qtH >> 2) + 1;   // 5..8
        const int nstL = (qtL >> 2) + 1;   // 1..4  (subset of heavy tiles)

        ushort* Ks = (ushort*)arena;                  // [key128][KSTR]
        ushort* Vs = (ushort*)(arena + 18432);        // [h64][VSTR]
        ushort* Ps = (ushort*)(arena + 35840);        // per-wave [q32][PSTR2]
        ushort* Psw = Ps + w * 32 * PSTR2;

        const ushort* kbb = kb  + (size_t)b * 65536;
        const ushort* vbb = vtb + (size_t)b * 65536;

        short8 qf0H[2], qf1H[2], qf0L[2], qf1L[2];
#pragma unroll
        for (int m = 0; m < 2; ++m) {
            const int qrH = b * 1024 + t0H + m * 16 + l15;
            qf0H[m] = *(const short8*)(qb + qrH * 64 + quad * 8);
            qf1H[m] = *(const short8*)(qb + qrH * 64 + 32 + quad * 8);
            const int qrL = b * 1024 + t0L + m * 16 + l15;
            qf0L[m] = *(const short8*)(qb + qrL * 64 + quad * 8);
            qf1L[m] = *(const short8*)(qb + qrL * 64 + 32 + quad * 8);
        }

        f32x4 oH[2][4] = {}, oL[2][4] = {};
        float liH[2][4] = {}, liL[2][4] = {};
        const float c1 = 0.125f * 1.4426950408889634f;
        const float c2 = 10.0f * 1.4426950408889634f;

        short8 kr[4], vr[4];
#pragma unroll
        for (int i = 0; i < 4; ++i) {
            int c = tid + i * 256;
            kr[i] = *(const short8*)(kbb + (c >> 3) * 64 + (c & 7) * 8);
            vr[i] = *(const short8*)(vbb + (c >> 4) * 1024 + (c & 15) * 8);
        }

        for (int it = 0; it < nstH; ++it) {
            const int s0 = it * 128;
            __syncthreads();   // WAR: previous iter's Ks/Vs reads complete
#pragma unroll
            for (int i = 0; i < 4; ++i) {
                int c = tid + i * 256;
                *(short8*)(Ks + (c >> 3) * KSTR + (c & 7) * 8) = kr[i];
                *(short8*)(Vs + (c >> 4) * VSTR + (c & 15) * 8) = vr[i];
            }
            __syncthreads();   // staging visible
            if (it + 1 < nstH) {
                const int sn = s0 + 128;
#pragma unroll
                for (int i = 0; i < 4; ++i) {
                    int c = tid + i * 256;
                    kr[i] = *(const short8*)(kbb + (sn + (c >> 3)) * 64 + (c & 7) * 8);
                    vr[i] = *(const short8*)(vbb + (c >> 4) * 1024 + sn + (c & 15) * 8);
                }
            }

            // shared K/V fragments for this wave's 32-key slice
            short8 kb0[2], kb1[2];
#pragma unroll
            for (int g = 0; g < 2; ++g) {
                const ushort* kp = Ks + (w * 32 + g * 16 + l15) * KSTR + quad * 8;
                kb0[g] = *(const short8*)(kp);
                kb1[g] = *(const short8*)(kp + 32);
            }
            short8 vbf[4];
#pragma unroll
            for (int ct = 0; ct < 4; ++ct)
                vbf[ct] = *(const short8*)(Vs + (ct * 16 + l15) * VSTR + w * 32 + quad * 8);

            // ---- job H ----
            {
                f32x4 s[2][2];
                __builtin_amdgcn_s_setprio(1);
#pragma unroll
                for (int g = 0; g < 2; ++g)
#pragma unroll
                    for (int m = 0; m < 2; ++m) {
                        f32x4 z = {};
                        z = __builtin_amdgcn_mfma_f32_16x16x32_bf16(qf0H[m], kb0[g], z, 0, 0, 0);
                        s[m][g] = __builtin_amdgcn_mfma_f32_16x16x32_bf16(qf1H[m], kb1[g], z, 0, 0, 0);
                    }
                __builtin_amdgcn_s_setprio(0);

                if (it + 1 < nstH) {
#pragma unroll
                    for (int m = 0; m < 2; ++m)
#pragma unroll
                        for (int g = 0; g < 2; ++g)
#pragma unroll
                            for (int r = 0; r < 4; ++r) {
                                float p = exp2f(s[m][g][r] * c1 - c2);
                                liH[m][r] += p;
                                Psw[(m * 16 + quad * 4 + r) * PSTR2 + g * 16 + l15] = f2bf(p);
                            }
                } else {
#pragma unroll
                    for (int m = 0; m < 2; ++m)
#pragma unroll
                        for (int g = 0; g < 2; ++g)
#pragma unroll
                            for (int r = 0; r < 4; ++r) {
                                const int trow = t0H + m * 16 + quad * 4 + r;
                                const int col = s0 + w * 32 + g * 16 + l15;
                                float p = (col <= trow) ? exp2f(s[m][g][r] * c1 - c2) : 0.f;
                                liH[m][r] += p;
                                Psw[(m * 16 + quad * 4 + r) * PSTR2 + g * 16 + l15] = f2bf(p);
                            }
                }

                short8 pa[2];
#pragma unroll
                for (int m = 0; m < 2; ++m)
                    pa[m] = *(const short8*)(Psw + (m * 16 + l15) * PSTR2 + quad * 8);

                __builtin_amdgcn_s_setprio(1);
#pragma unroll
                for (int m = 0; m < 2; ++m)
#pragma unroll
                    for (int ct = 0; ct < 4; ++ct)
                        oH[m][ct] = __builtin_amdgcn_mfma_f32_16x16x32_bf16(pa[m], vbf[ct], oH[m][ct], 0, 0, 0);
                __builtin_amdgcn_s_setprio(0);
            }

            // ---- job L (active on the subset of tiles) ----
            if (it < nstL) {
                f32x4 s[2][2];
                __builtin_amdgcn_s_setprio(1);
#pragma unroll
                for (int g = 0; g < 2; ++g)
#pragma unroll
                    for (int m = 0; m < 2; ++m) {
                        f32x4 z = {};
                        z = __builtin_amdgcn_mfma_f32_16x16x32_bf16(qf0L[m], kb0[g], z, 0, 0, 0);
                        s[m][g] = __builtin_amdgcn_mfma_f32_16x16x32_bf16(qf1L[m], kb1[g], z, 0, 0, 0);
                    }
                __builtin_amdgcn_s_setprio(0);

                if (it + 1 < nstL) {
#pragma unroll
                    for (int m = 0; m < 2; ++m)
#pragma unroll
                        for (int g = 0; g < 2; ++g)
#pragma unroll
                            for (int r = 0; r < 4; ++r) {
                                float p = exp2f(s[m][g][r] * c1 - c2);
                                liL[m][r] += p;
                                Psw[(m * 16 + quad * 4 + r) * PSTR2 + g * 16 + l15] = f2bf(p);
                            }
                } else {
#pragma unroll
                    for (int m = 0; m < 2; ++m)
#pragma unroll
                        for (int g = 0; g < 2; ++g)
#pragma unroll
                            for (int r = 0; r < 4; ++r) {
                                const int trow = t0L + m * 16 + quad * 4 + r;
                                const int col = s0 + w * 32 + g * 16 + l15;
                                float p = (col <= trow) ? exp2f(s[m][g][r] * c1 - c2) : 0.f;
                                liL[m][r] += p;
                                Psw[(m * 16 + quad * 4 + r) * PSTR2 + g * 16 + l15] = f2bf(p);
                            }
                }

                short8 pa[2];
#pragma unroll
                for (int m = 0; m < 2; ++m)
                    pa[m] = *(const short8*)(Psw + (m * 16 + l15) * PSTR2 + quad * 8);

                __builtin_amdgcn_s_setprio(1);
#pragma unroll
                for (int m = 0; m < 2; ++m)
#pragma unroll
                    for (int ct = 0; ct < 4; ++ct)
                        oL[m][ct] = __builtin_amdgcn_mfma_f32_16x16x32_bf16(pa[m], vbf[ct], oL[m][ct], 0, 0, 0);
                __builtin_amdgcn_s_setprio(0);
            }
        }

        attn_epilogue(arena, oH, liH, w, quad, l15, t0H, b, out);
        attn_epilogue(arena, oL, liL, w, quad, l15, t0L, b, out);
    }
}

// ---------------------------------------------------------------------------
extern "C" void kernel_launch(void* const* d_in, const int* in_sizes, int n_in,
                              void* d_out, int out_size, void* d_ws, size_t ws_size,
                              hipStream_t stream) {
    const float* x  = (const float*)d_in[0];
    const float* Wk = (const float*)d_in[1];
    const float* Wq = (const float*)d_in[2];
    const float* Wv = (const float*)d_in[3];

    char* ws = (char*)d_ws;
    ushort* wf  = (ushort*)ws;                                   // 144 KiB swizzled weights
    unsigned* sem = (unsigned*)(ws + 200 * 1024);                // 32 batch semaphores
    ushort* kb  = (ushort*)(ws + 256 * 1024);                    // 4 MiB
    ushort* qb  = (ushort*)(ws + 256 * 1024 + 4u * 1024 * 1024); // 4 MiB
    ushort* vtb = (ushort*)(ws + 256 * 1024 + 8u * 1024 * 1024); // 4 MiB

    wswz<<<dim3(3, 12), dim3(256), 0, stream>>>(Wk, Wq, Wv, wf, sem);
    qkattn<<<dim3(512), dim3(256), 0, stream>>>(x, wf, kb, qb, vtb, (float*)d_out, sem);
}

// Round 8
// 119.678 us; speedup vs baseline: 1.8430x; 1.8430x over previous
//
#include <hip/hip_runtime.h>
#include <hip/hip_bf16.h>

#define BB 32
#define TT 1024
#define CCH 384
#define HH 64

typedef short short8 __attribute__((ext_vector_type(8)));
typedef float f32x4 __attribute__((ext_vector_type(4)));
typedef unsigned short ushort;

// RNE f32->bf16 via the official cast (same rounding as the previous
// bit-twiddle); scalar-cast form lets the compiler fuse adjacent converts
// into v_cvt_pk_bf16_f32 (m240: compiler handles it; hand-written asm and
// integer twiddles can't be pattern-matched).
static __device__ __forceinline__ ushort f2bf(float f) {
    union { __hip_bfloat16 h; ushort u; } v;
    v.h = __float2bfloat16(f);
    return v.u;
}

// ---------------------------------------------------------------------------
// Kernel 1: swizzle the three f32 [384,64] weight matrices into MFMA
// B-fragment-contiguous bf16 layout. (r6-verified)
// ---------------------------------------------------------------------------
__global__ void wswz(const float* __restrict__ Wk, const float* __restrict__ Wq,
                     const float* __restrict__ Wv, ushort* __restrict__ wf) {
    const int mat = blockIdx.x, ks = blockIdx.y;
    const float* W = (mat == 0) ? Wk : ((mat == 1) ? Wq : Wv);
    const int t = threadIdx.x;
    const int ct = t >> 6, lane = t & 63, quad = lane >> 4, l15 = lane & 15;
    const int col = ct * 16 + l15;
    short8 d;
#pragma unroll
    for (int j = 0; j < 8; ++j)
        d[j] = (short)f2bf(W[(ks * 32 + quad * 8 + j) * 64 + col]);
    *(short8*)(wf + (((mat * 12 + ks) * 4 + ct) << 9) + lane * 8) = d;
}

// ---------------------------------------------------------------------------
// Kernel 2: fused QKV projection. (r6-verified + VS_STRIDE 68->66:
// r7's counters exposed SQ_LDS_BANK_CONFLICT=1.39M; the only >=4-way path
// is the vs transpose read — with stride 34 words the four rbase groups
// (0/16/32/48 rows) are 544 words apart == 0 mod 32 -> same banks, 4-way.
// Stride 33 words (66 u16) puts them 16 apart -> 2-way = free (m136).
// All vs accesses are scalar u16, so no alignment constraint.)
// ---------------------------------------------------------------------------
#define XSTR 388
#define VS_STRIDE 66

__global__ __launch_bounds__(256, 2) void qkv(const float* __restrict__ x,
                                              const ushort* __restrict__ wf,
                                              ushort* __restrict__ kb,
                                              ushort* __restrict__ qb,
                                              ushort* __restrict__ vtb) {
    const int r0 = blockIdx.x * 64;
    const int tid = threadIdx.x;
    const int wv = tid >> 6, lane = tid & 63, l15 = lane & 15, quad = lane >> 4;

    __shared__ ushort xs[64 * XSTR];

#pragma unroll
    for (int kb3 = 0; kb3 < 3; ++kb3) {
        const int kbase = kb3 * 128;
        const int seg = (tid & 7) * 16;
#pragma unroll
        for (int i = 0; i < 2; ++i) {
            const int r = (tid >> 3) + 32 * i;
            const float* src = x + (size_t)(r0 + r) * CCH + kbase + seg;
            f32x4 v0 = *(const f32x4*)(src);
            f32x4 v1 = *(const f32x4*)(src + 4);
            f32x4 v2 = *(const f32x4*)(src + 8);
            f32x4 v3 = *(const f32x4*)(src + 12);
            short8 p0, p1;
#pragma unroll
            for (int j = 0; j < 4; ++j) {
                p0[j]     = (short)f2bf(v0[j]);
                p0[j + 4] = (short)f2bf(v1[j]);
                p1[j]     = (short)f2bf(v2[j]);
                p1[j + 4] = (short)f2bf(v3[j]);
            }
            *(short8*)(xs + r * XSTR + kbase + seg) = p0;
            *(short8*)(xs + r * XSTR + kbase + seg + 8) = p1;
        }
    }
    __syncthreads();

    f32x4 acc[12] = {};   // [mat*4+ct]
    short8 bf[2][12];
#pragma unroll
    for (int m = 0; m < 3; ++m)
#pragma unroll
        for (int ct = 0; ct < 4; ++ct)
            bf[0][m * 4 + ct] = *(const short8*)(wf + (((m * 12 + 0) * 4 + ct) << 9) + lane * 8);

#pragma unroll
    for (int ks = 0; ks < 12; ++ks) {
        short8 a = *(const short8*)(xs + (wv * 16 + l15) * XSTR + ks * 32 + quad * 8);
        if (ks < 11) {
#pragma unroll
            for (int m = 0; m < 3; ++m)
#pragma unroll
                for (int ct = 0; ct < 4; ++ct)
                    bf[(ks + 1) & 1][m * 4 + ct] =
                        *(const short8*)(wf + (((m * 12 + ks + 1) * 4 + ct) << 9) + lane * 8);
        }
#pragma unroll
        for (int f = 0; f < 12; ++f)
            acc[f] = __builtin_amdgcn_mfma_f32_16x16x32_bf16(a, bf[ks & 1][f], acc[f], 0, 0, 0);
    }

#pragma unroll
    for (int ct = 0; ct < 4; ++ct) {
#pragma unroll
        for (int r = 0; r < 4; ++r) {
            int row = r0 + wv * 16 + quad * 4 + r;
            int col = ct * 16 + l15;
            kb[row * 64 + col] = f2bf(acc[0 + ct][r]);
            qb[row * 64 + col] = f2bf(acc[4 + ct][r]);
        }
    }
    __syncthreads();
    ushort* vs = xs;
#pragma unroll
    for (int ct = 0; ct < 4; ++ct)
#pragma unroll
        for (int r = 0; r < 4; ++r)
            vs[(wv * 16 + quad * 4 + r) * VS_STRIDE + ct * 16 + l15] = f2bf(acc[8 + ct][r]);
    __syncthreads();
    {
        const int col = tid >> 2;
        const int rbase = (tid & 3) * 16;
        short8 d0, d1;
#pragma unroll
        for (int j = 0; j < 8; ++j) {
            d0[j] = (short)vs[(rbase + j) * VS_STRIDE + col];
            d1[j] = (short)vs[(rbase + 8 + j) * VS_STRIDE + col];
        }
        const int b = r0 >> 10;
        const int t = (r0 & 1023) + rbase;
        *(short8*)(vtb + b * 65536 + col * 1024 + t) = d0;
        *(short8*)(vtb + b * 65536 + col * 1024 + t + 8) = d1;
    }
}

// ---------------------------------------------------------------------------
// Kernel 3: fused causal attention — 32-ROW Q-TILES, 3 BLOCKS/CU.
// (r6-verified body, byte-identical apart from the shared f2bf change)
// ---------------------------------------------------------------------------
#define PSTR2 40   // u16 stride of P rows (80 B): 2-way bank pattern (free)
#define KSTR 72
#define VSTR 136

__global__ __launch_bounds__(256, 3) void attn(const ushort* __restrict__ qb,
                                               const ushort* __restrict__ kb,
                                               const ushort* __restrict__ vtb,
                                               float* __restrict__ out) {
    const int y = blockIdx.y;
    int qt;                                  // 32-row q-tile index, 0..31
    if (y < 8)       qt = 31 - y;            // 8,8,8,8,7,7,7,7 units
    else if (y < 16) qt = y - 8;             // 1,1,1,1,2,2,2,2
    else if (y < 24) qt = 39 - y;            // 6,6,6,6,5,5,5,5
    else             qt = y - 16;            // 3,3,3,3,4,4,4,4
    const int b = blockIdx.x;
    const int t0 = qt * 32;
    const int tid = threadIdx.x;
    const int w = tid >> 6, lane = tid & 63, l15 = lane & 15, quad = lane >> 4;

    __shared__ __align__(16) char arena[46080];
    ushort* Ks = (ushort*)arena;                  // [key128][KSTR]
    ushort* Vs = (ushort*)(arena + 18432);        // [h64][VSTR]
    ushort* Ps = (ushort*)(arena + 35840);        // per-wave [q32][PSTR2]
    ushort* Psw = Ps + w * 32 * PSTR2;

    const ushort* kbb = kb  + (size_t)b * 65536;
    const ushort* vbb = vtb + (size_t)b * 65536;

    short8 qf0[2], qf1[2];
#pragma unroll
    for (int m = 0; m < 2; ++m) {
        const int qrow = b * 1024 + t0 + m * 16 + l15;
        qf0[m] = *(const short8*)(qb + qrow * 64 + quad * 8);
        qf1[m] = *(const short8*)(qb + qrow * 64 + 32 + quad * 8);
    }

    f32x4 o[2][4] = {};      // [q-sub m][h-ct] partial over this wave's keys
    float li[2][4] = {};     // [m][r] per-lane partial row sums
    const float c1 = 0.125f * 1.4426950408889634f;  // scale * log2(e)
    const float c2 = 10.0f * 1.4426950408889634f;   // fixed shift M=10

    const int nst = (qt >> 2) + 1;           // number of 128-key tiles

    short8 kr[4], vr[4];
#pragma unroll
    for (int i = 0; i < 4; ++i) {
        int c = tid + i * 256;
        kr[i] = *(const short8*)(kbb + (c >> 3) * 64 + (c & 7) * 8);
        vr[i] = *(const short8*)(vbb + (c >> 4) * 1024 + (c & 15) * 8);
    }

    for (int it = 0; it < nst; ++it) {
        const int s0 = it * 128;
        __syncthreads();   // WAR: previous iter's Ks/Vs reads complete
#pragma unroll
        for (int i = 0; i < 4; ++i) {
            int c = tid + i * 256;
            *(short8*)(Ks + (c >> 3) * KSTR + (c & 7) * 8) = kr[i];
            *(short8*)(Vs + (c >> 4) * VSTR + (c & 15) * 8) = vr[i];
        }
        __syncthreads();   // staging visible
        if (it + 1 < nst) {
            const int sn = s0 + 128;
#pragma unroll
            for (int i = 0; i < 4; ++i) {
                int c = tid + i * 256;
                kr[i] = *(const short8*)(kbb + (sn + (c >> 3)) * 64 + (c & 7) * 8);
                vr[i] = *(const short8*)(vbb + (c >> 4) * 1024 + sn + (c & 15) * 8);
            }
        }

        // S = Q K^T on this wave's 32-key slice; B-frags reused across m
        f32x4 s[2][2];
        __builtin_amdgcn_s_setprio(1);
#pragma unroll
        for (int g = 0; g < 2; ++g) {
            const ushort* kp = Ks + (w * 32 + g * 16 + l15) * KSTR + quad * 8;
            short8 b0 = *(const short8*)(kp);
            short8 b1 = *(const short8*)(kp + 32);
#pragma unroll
            for (int m = 0; m < 2; ++m) {
                f32x4 z = {};
                z = __builtin_amdgcn_mfma_f32_16x16x32_bf16(qf0[m], b0, z, 0, 0, 0);
                s[m][g] = __builtin_amdgcn_mfma_f32_16x16x32_bf16(qf1[m], b1, z, 0, 0, 0);
            }
        }
        __builtin_amdgcn_s_setprio(0);

        // fixed-shift softmax: p = exp2(s*c1 - c2); mask only on diag tile
        if (it + 1 < nst) {
#pragma unroll
            for (int m = 0; m < 2; ++m)
#pragma unroll
                for (int g = 0; g < 2; ++g)
#pragma unroll
                    for (int r = 0; r < 4; ++r) {
                        float p = exp2f(s[m][g][r] * c1 - c2);
                        li[m][r] += p;
                        Psw[(m * 16 + quad * 4 + r) * PSTR2 + g * 16 + l15] = f2bf(p);
                    }
        } else {
#pragma unroll
            for (int m = 0; m < 2; ++m)
#pragma unroll
                for (int g = 0; g < 2; ++g)
#pragma unroll
                    for (int r = 0; r < 4; ++r) {
                        const int trow = t0 + m * 16 + quad * 4 + r;
                        const int col = s0 + w * 32 + g * 16 + l15;
                        float p = (col <= trow) ? exp2f(s[m][g][r] * c1 - c2) : 0.f;
                        li[m][r] += p;
                        Psw[(m * 16 + quad * 4 + r) * PSTR2 + g * 16 + l15] = f2bf(p);
                    }
        }

        // P: C-layout -> wave-local LDS -> A-layout (no barrier: same wave)
        short8 pa[2];
#pragma unroll
        for (int m = 0; m < 2; ++m)
            pa[m] = *(const short8*)(Psw + (m * 16 + l15) * PSTR2 + quad * 8);

        // O += P V on this wave's key slice; V B-frags reused across m
        __builtin_amdgcn_s_setprio(1);
        short8 vbf[4];
#pragma unroll
        for (int ct = 0; ct < 4; ++ct)
            vbf[ct] = *(const short8*)(Vs + (ct * 16 + l15) * VSTR + w * 32 + quad * 8);
#pragma unroll
        for (int m = 0; m < 2; ++m)
#pragma unroll
            for (int ct = 0; ct < 4; ++ct)
                o[m][ct] = __builtin_amdgcn_mfma_f32_16x16x32_bf16(pa[m], vbf[ct], o[m][ct], 0, 0, 0);
        __builtin_amdgcn_s_setprio(0);
    }

    __syncthreads();   // all waves done with Ks/Vs/Ps before arena reuse

    // in-wave reduce li across the 16 l15 lanes (full row sums)
#pragma unroll
    for (int m = 0; m < 2; ++m)
#pragma unroll
        for (int r = 0; r < 4; ++r) {
            float rs = li[m][r];
#pragma unroll
            for (int off = 1; off < 16; off <<= 1)
                rs += __shfl_xor(rs, off);
            li[m][r] = rs;
        }

    // publish all (w, m) partials; combine by addition (fixed-shift softmax)
    float* slotO = (float*)arena;              // [8][4][16][17] f32
    float* slotL = (float*)(arena + 34816);    // [8][16] f32
#pragma unroll
    for (int m = 0; m < 2; ++m) {
        const int sl = w * 2 + m;
#pragma unroll
        for (int ct = 0; ct < 4; ++ct)
#pragma unroll
            for (int r = 0; r < 4; ++r)
                slotO[(sl * 4 + ct) * 272 + (quad * 4 + r) * 17 + l15] = o[m][ct][r];
        if (l15 == 0)
#pragma unroll
            for (int r = 0; r < 4; ++r)
                slotL[sl * 16 + quad * 4 + r] = li[m][r];
    }
    __syncthreads();

    // wave w finalizes subtile mh = w>>1, column pair cb = (w&1)*2
    {
        const int mh = w >> 1, cb = (w & 1) * 2;
#pragma unroll
        for (int r = 0; r < 4; ++r) {
            float lsum = 0.f;
#pragma unroll
            for (int wp = 0; wp < 4; ++wp)
                lsum += slotL[(wp * 2 + mh) * 16 + quad * 4 + r];
            const float inv = 1.0f / lsum;
            const int t = t0 + mh * 16 + quad * 4 + r;
#pragma unroll
            for (int cc = 0; cc < 2; ++cc) {
                const int ct = cb + cc;
                float v = 0.f;
#pragma unroll
                for (int wp = 0; wp < 4; ++wp)
                    v += slotO[((wp * 2 + mh) * 4 + ct) * 272 + (quad * 4 + r) * 17 + l15];
                out[b * 65536 + t * 64 + ct * 16 + l15] = v * inv;
            }
        }
    }
}

// ---------------------------------------------------------------------------
extern "C" void kernel_launch(void* const* d_in, const int* in_sizes, int n_in,
                              void* d_out, int out_size, void* d_ws, size_t ws_size,
                              hipStream_t stream) {
    const float* x  = (const float*)d_in[0];
    const float* Wk = (const float*)d_in[1];
    const float* Wq = (const float*)d_in[2];
    const float* Wv = (const float*)d_in[3];

    char* ws = (char*)d_ws;
    ushort* wf  = (ushort*)ws;                                   // 144 KiB swizzled weights
    ushort* kb  = (ushort*)(ws + 256 * 1024);                    // 4 MiB
    ushort* qb  = (ushort*)(ws + 256 * 1024 + 4u * 1024 * 1024); // 4 MiB
    ushort* vtb = (ushort*)(ws + 256 * 1024 + 8u * 1024 * 1024); // 4 MiB

    wswz<<<dim3(3, 12), dim3(256), 0, stream>>>(Wk, Wq, Wv, wf);
    qkv<<<dim3(512), dim3(256), 0, stream>>>(x, wf, kb, qb, vtb);
    attn<<<dim3(32, 32), dim3(256), 0, stream>>>(qb, kb, vtb, (float*)d_out);
}